// Round 4
// baseline (337.046 us; speedup 1.0000x reference)
//
#include <hip/hip_runtime.h>
#include <math.h>

#define NB 4
#define NC 4
#define NF 257
#define NFR 1024
#define JPT 4
#define NTOT (NB * NC * NF * NFR)
#define EPSV 1e-3f
#define EPS_MODEL 1e-5f

// Module-scope scratch: allocated at load time, graph-capture safe, fully
// rewritten on every kernel_launch call (no cross-call state dependence).
__device__ float g_Spart[8 * NB * NC * NFR];  // per-(fchunk) partial column sums
__device__ float g_S[NB * NC * NFR];          // S[b,c,n] = sum_f |X[b,c,f,n]|^2
__device__ float g_gP[96];                    // g_e, P_e per (b,c), e=0..2

// ---------------------------------------------------------------------------
// K1: partial column sums over freq chunks (no atomics -> deterministic)
// ---------------------------------------------------------------------------
__global__ __launch_bounds__(256) void k_colsum(const float* __restrict__ Xr,
                                                const float* __restrict__ Xi) {
  int u = blockIdx.x * 256 + threadIdx.x;  // bc*1024 + n, < 16384
  int fc = blockIdx.y;
  int f0 = fc * 33;
  int f1 = f0 + 33; if (f1 > NF) f1 = NF;
  int bc = u >> 10, n = u & 1023;
  int base = bc * NF * NFR + n;
  float s = 0.f;
  for (int f = f0; f < f1; ++f) {
    float a = Xr[base + f * NFR];
    float b = Xi[base + f * NFR];
    s += a * a + b * b;
  }
  g_Spart[fc * (NB * NC * NFR) + u] = s;
}

// K1b: reduce the 8 partials
__global__ __launch_bounds__(256) void k_red() {
  int u = blockIdx.x * 256 + threadIdx.x;
  float s = 0.f;
#pragma unroll
  for (int fc = 0; fc < 8; ++fc) s += g_Spart[fc * (NB * NC * NFR) + u];
  g_S[u] = s;
}

// ---------------------------------------------------------------------------
// K2: per (b,c): s0 = mean |X|^2 over (F,N); then g_e, P_e for e=0..2
// ---------------------------------------------------------------------------
__global__ __launch_bounds__(256) void k_gp() {
  int bc = blockIdx.x;
  int tid = threadIdx.x;
  float p = 0.f;
#pragma unroll
  for (int j = 0; j < JPT; ++j) p += g_S[bc * NFR + tid + 256 * j];
#pragma unroll
  for (int off = 32; off; off >>= 1) p += __shfl_xor(p, off, 64);
  __shared__ float r[4];
  if ((tid & 63) == 0) r[tid >> 6] = p;
  __syncthreads();
  if (tid == 0) {
    float s0 = (r[0] + r[1] + r[2] + r[3]) / (float)(NF * NFR);
    float P = 1.f;
#pragma unroll
    for (int e = 0; e < 3; ++e) {
      float g = fmaxf(s0 / P, 1e-5f);
      g_gP[e * 32 + bc] = g;
      g_gP[e * 32 + 16 + bc] = P;
      P *= g;
    }
  }
}

// ---------------------------------------------------------------------------
// Main: one block per (b,f). Xc[4ch][1024fr] in registers across all 36 ISS
// sweeps; 12-float block reduction per sweep; W (4x4 cplx) in LDS; final 4x4
// complex solve + output real(Xc*a) (or interleaved if nout >= 2*NTOT).
// ---------------------------------------------------------------------------
__global__ __launch_bounds__(256) void k_main(
    const float* __restrict__ Xr, const float* __restrict__ Xi,
    float* __restrict__ out, int nout) {
  const int blk = blockIdx.x;
  const int b = blk / NF, f = blk % NF;
  const int tid = threadIdx.x;
  const int lane = tid & 63, wvid = tid >> 6;
  const float invN = 1.f / (float)NFR;

  __shared__ float red[4][12];
  __shared__ float Wre[NC][NC], Wim[NC][NC];
  __shared__ float abc[8];

  float xcr[NC][JPT], xci[NC][JPT];
  int rowbase[NC];
#pragma unroll
  for (int c = 0; c < NC; ++c) {
    rowbase[c] = ((b * NC + c) * NF + f) * NFR;
#pragma unroll
    for (int j = 0; j < JPT; ++j) {
      int n = tid + 256 * j;
      xcr[c][j] = Xr[rowbase[c] + n];
      xci[c][j] = Xi[rowbase[c] + n];
    }
  }
  if (tid < 16) {
    Wre[tid >> 2][tid & 3] = ((tid >> 2) == (tid & 3)) ? 1.f : 0.f;
    Wim[tid >> 2][tid & 3] = 0.f;
  }

  float w[NC][JPT];

  for (int e = 0; e < 3; ++e) {
    // ---- per-epoch weights (closed form from S, g, P) ----
#pragma unroll
    for (int c = 0; c < NC; ++c) {
      float g = g_gP[e * 32 + b * NC + c];
      float P = g_gP[e * 32 + 16 + b * NC + c];
      float sc = 1.f / P;
#pragma unroll
      for (int j = 0; j < JPT; ++j) {
        float Sv = g_S[(b * NC + c) * NFR + tid + 256 * j];
        w[c][j] = g / fmaxf(2.f * sqrtf(Sv * sc), EPS_MODEL);
      }
    }

    // ================= type-1 sweeps =================
    for (int src = 0; src < NC; ++src) {
      float p[12];
#pragma unroll
      for (int k = 0; k < 12; ++k) p[k] = 0.f;
#pragma unroll
      for (int j = 0; j < JPT; ++j) {
        float xsr = xcr[src][j], xsi = xci[src][j];
        float msq = xsr * xsr + xsi * xsi;
#pragma unroll
        for (int c = 0; c < NC; ++c) {
          float wvv = w[c][j];
          p[c]     += wvv * (xcr[c][j] * xsr + xci[c][j] * xsi);
          p[4 + c] += wvv * (xci[c][j] * xsr - xcr[c][j] * xsi);
          p[8 + c] += wvv * msq;
        }
      }
#pragma unroll
      for (int k = 0; k < 12; ++k) {
#pragma unroll
        for (int off = 32; off; off >>= 1) p[k] += __shfl_xor(p[k], off, 64);
      }
      __syncthreads();
      if (lane == 0) {
#pragma unroll
        for (int k = 0; k < 12; ++k) red[wvid][k] = p[k];
      }
      __syncthreads();

      float vr[NC], vi[NC];
#pragma unroll
      for (int c = 0; c < NC; ++c) {
        float nr = (red[0][c] + red[1][c] + red[2][c] + red[3][c]) * invN;
        float ni = (red[0][4 + c] + red[1][4 + c] + red[2][4 + c] + red[3][4 + c]) * invN;
        float dd = (red[0][8 + c] + red[1][8 + c] + red[2][8 + c] + red[3][8 + c]) * invN;
        float den = fmaxf(dd, EPSV);
        if (c == src) {
          vr[c] = 1.f - 1.f / sqrtf(den);
          vi[c] = 0.f;
        } else {
          vr[c] = nr / den;
          vi[c] = ni / den;
        }
      }
#pragma unroll
      for (int j = 0; j < JPT; ++j) {
        float xsr = xcr[src][j], xsi = xci[src][j];
#pragma unroll
        for (int c = 0; c < NC; ++c) {
          xcr[c][j] -= vr[c] * xsr - vi[c] * xsi;
          xci[c][j] -= vr[c] * xsi + vi[c] * xsr;
        }
      }
      if (tid == 0) {
#pragma unroll
        for (int jj = 0; jj < NC; ++jj) {
          float wsr = Wre[src][jj], wsi = Wim[src][jj];
#pragma unroll
          for (int c = 0; c < NC; ++c) {
            Wre[c][jj] -= vr[c] * wsr - vi[c] * wsi;
            Wim[c][jj] -= vr[c] * wsi + vi[c] * wsr;
          }
        }
      }
    }

    // ================= type-2 sweeps =================
    for (int src = 0; src < NC; ++src) {
      const int sbase = ((b * NC + src) * NF + f) * NFR;
      for (int tap = 0; tap < 2; ++tap) {
        float xstr[JPT], xsti[JPT];
#pragma unroll
        for (int j = 0; j < JPT; ++j) {
          int m = tid + 256 * j - 3 + tap;  // X_bar[...,tap,n] = X[..., n+tap-3]
          if (m >= 0) {
            xstr[j] = Xr[sbase + m];
            xsti[j] = Xi[sbase + m];
          } else {
            xstr[j] = 0.f;
            xsti[j] = 0.f;
          }
        }
        float p[12];
#pragma unroll
        for (int k = 0; k < 12; ++k) p[k] = 0.f;
#pragma unroll
        for (int j = 0; j < JPT; ++j) {
          float msq = xstr[j] * xstr[j] + xsti[j] * xsti[j];
#pragma unroll
          for (int c = 0; c < NC; ++c) {
            float wvv = w[c][j];
            p[c]     += wvv * (xcr[c][j] * xstr[j] + xci[c][j] * xsti[j]);
            p[4 + c] += wvv * (xci[c][j] * xstr[j] - xcr[c][j] * xsti[j]);
            p[8 + c] += wvv * msq;
          }
        }
#pragma unroll
        for (int k = 0; k < 12; ++k) {
#pragma unroll
          for (int off = 32; off; off >>= 1) p[k] += __shfl_xor(p[k], off, 64);
        }
        __syncthreads();
        if (lane == 0) {
#pragma unroll
          for (int k = 0; k < 12; ++k) red[wvid][k] = p[k];
        }
        __syncthreads();

        float vr[NC], vi[NC];
#pragma unroll
        for (int c = 0; c < NC; ++c) {
          float nr = (red[0][c] + red[1][c] + red[2][c] + red[3][c]) * invN;
          float ni = (red[0][4 + c] + red[1][4 + c] + red[2][4 + c] + red[3][4 + c]) * invN;
          float dd = red[0][8 + c] + red[1][8 + c] + red[2][8 + c] + red[3][8 + c];  // SUM, not mean
          float den = fmaxf(dd, EPSV);
          vr[c] = nr / den;
          vi[c] = ni / den;
        }
#pragma unroll
        for (int j = 0; j < JPT; ++j) {
#pragma unroll
          for (int c = 0; c < NC; ++c) {
            xcr[c][j] -= vr[c] * xstr[j] - vi[c] * xsti[j];
            xci[c][j] -= vr[c] * xsti[j] + vi[c] * xstr[j];
          }
        }
      }
    }
  }  // epochs

  // ---- solve W^T a = e1 (4x4 complex, partial pivoting), A[i][j] = W[j][i] ----
  __syncthreads();
  if (tid == 0) {
    float Ar[4][4], Ai[4][4];
    float br[4] = {1.f, 0.f, 0.f, 0.f}, bi[4] = {0.f, 0.f, 0.f, 0.f};
#pragma unroll
    for (int i = 0; i < 4; ++i)
#pragma unroll
      for (int j = 0; j < 4; ++j) {
        Ar[i][j] = Wre[j][i];
        Ai[i][j] = Wim[j][i];
      }
    for (int k = 0; k < 4; ++k) {
      int piv = k;
      float best = Ar[k][k] * Ar[k][k] + Ai[k][k] * Ai[k][k];
      for (int i = k + 1; i < 4; ++i) {
        float m = Ar[i][k] * Ar[i][k] + Ai[i][k] * Ai[i][k];
        if (m > best) { best = m; piv = i; }
      }
      if (piv != k) {
        for (int j = 0; j < 4; ++j) {
          float t = Ar[k][j]; Ar[k][j] = Ar[piv][j]; Ar[piv][j] = t;
          t = Ai[k][j]; Ai[k][j] = Ai[piv][j]; Ai[piv][j] = t;
        }
        float t = br[k]; br[k] = br[piv]; br[piv] = t;
        t = bi[k]; bi[k] = bi[piv]; bi[piv] = t;
      }
      float dr = Ar[k][k], di = Ai[k][k];
      float inv = 1.f / (dr * dr + di * di);
      for (int i = k + 1; i < 4; ++i) {
        float fr = (Ar[i][k] * dr + Ai[i][k] * di) * inv;
        float fi = (Ai[i][k] * dr - Ar[i][k] * di) * inv;
        for (int j = k; j < 4; ++j) {
          Ar[i][j] -= fr * Ar[k][j] - fi * Ai[k][j];
          Ai[i][j] -= fr * Ai[k][j] + fi * Ar[k][j];
        }
        br[i] -= fr * br[k] - fi * bi[k];
        bi[i] -= fr * bi[k] + fi * br[k];
      }
    }
    float ar[4], ai[4];
    for (int k = 3; k >= 0; --k) {
      float sr = br[k], si = bi[k];
      for (int j = k + 1; j < 4; ++j) {
        sr -= Ar[k][j] * ar[j] - Ai[k][j] * ai[j];
        si -= Ar[k][j] * ai[j] + Ai[k][j] * ar[j];
      }
      float dr = Ar[k][k], di = Ai[k][k];
      float inv = 1.f / (dr * dr + di * di);
      ar[k] = (sr * dr + si * di) * inv;
      ai[k] = (si * dr - sr * di) * inv;
    }
#pragma unroll
    for (int c = 0; c < 4; ++c) { abc[c] = ar[c]; abc[4 + c] = ai[c]; }
  }
  __syncthreads();

  // ---- output: d_out holds NTOT float32 = real(Xc*a) per element
  //      (fallback: interleaved complex pairs if nout >= 2*NTOT) ----
  const bool interleaved = (nout >= 2 * NTOT);
#pragma unroll
  for (int c = 0; c < NC; ++c) {
    float ar = abc[c], ai2 = abc[4 + c];
#pragma unroll
    for (int j = 0; j < JPT; ++j) {
      int idx = rowbase[c] + tid + 256 * j;
      float orr = xcr[c][j] * ar - xci[c][j] * ai2;
      if (interleaved) {
        float oii = xcr[c][j] * ai2 + xci[c][j] * ar;
        reinterpret_cast<float2*>(out)[idx] = make_float2(orr, oii);
      } else if (idx < nout) {
        out[idx] = orr;
      }
    }
  }
}

// ---------------------------------------------------------------------------
extern "C" void kernel_launch(void* const* d_in, const int* in_sizes, int n_in,
                              void* d_out, int out_size, void* d_ws, size_t ws_size,
                              hipStream_t stream) {
  const float* Xr = (const float*)d_in[0];
  const float* Xi = (const float*)d_in[1];
  float* out = (float*)d_out;

  dim3 g1(64, 8);
  k_colsum<<<g1, 256, 0, stream>>>(Xr, Xi);
  k_red<<<64, 256, 0, stream>>>();
  k_gp<<<16, 256, 0, stream>>>();
  k_main<<<NB * NF, 256, 0, stream>>>(Xr, Xi, out, out_size);
}

// Round 5
// 259.373 us; speedup vs baseline: 1.2995x; 1.2995x over previous
//
#include <hip/hip_runtime.h>
#include <math.h>

#define NB 4
#define NC 4
#define NF 257
#define NFR 1024
#define NTOT (NB * NC * NF * NFR)
#define EPSV 1e-3f
#define EPS_MODEL 1e-5f

// Module-scope scratch: allocated at load, graph-capture safe, fully
// rewritten every call.
__device__ float g_Spart[8 * NB * NC * NFR];
__device__ float g_S[NB * NC * NFR];
__device__ float g_gP[96];

// Wave-wide sum via DPP (VALU pipe, no LDS traffic). Lane 63 holds the sum.
__device__ __forceinline__ float dpp_red_sum(float v) {
  v += __int_as_float(__builtin_amdgcn_update_dpp(0, __float_as_int(v), 0x111, 0xf, 0xf, true)); // row_shr:1
  v += __int_as_float(__builtin_amdgcn_update_dpp(0, __float_as_int(v), 0x112, 0xf, 0xf, true)); // row_shr:2
  v += __int_as_float(__builtin_amdgcn_update_dpp(0, __float_as_int(v), 0x114, 0xf, 0xf, true)); // row_shr:4
  v += __int_as_float(__builtin_amdgcn_update_dpp(0, __float_as_int(v), 0x118, 0xf, 0xf, true)); // row_shr:8
  v += __int_as_float(__builtin_amdgcn_update_dpp(0, __float_as_int(v), 0x142, 0xa, 0xf, true)); // row_bcast:15
  v += __int_as_float(__builtin_amdgcn_update_dpp(0, __float_as_int(v), 0x143, 0xc, 0xf, true)); // row_bcast:31
  return v;
}

// ---------------------------------------------------------------------------
// K1: partial column sums over freq chunks, float4-vectorized.
// grid (16, 8): x covers bc*256 quad-frames, y = freq chunk of 33.
// ---------------------------------------------------------------------------
__global__ __launch_bounds__(256) void k_colsum(const float* __restrict__ Xr,
                                                const float* __restrict__ Xi) {
  int u = blockIdx.x * 256 + threadIdx.x;  // bc*256 + q, < 4096
  int fc = blockIdx.y;
  int f0 = fc * 33;
  int f1 = f0 + 33; if (f1 > NF) f1 = NF;
  int bc = u >> 8, q = u & 255;  // frames 4q..4q+3
  float4 s = make_float4(0.f, 0.f, 0.f, 0.f);
  for (int f = f0; f < f1; ++f) {
    float4 a = reinterpret_cast<const float4*>(Xr + (bc * NF + f) * NFR)[q];
    float4 b = reinterpret_cast<const float4*>(Xi + (bc * NF + f) * NFR)[q];
    s.x += a.x * a.x + b.x * b.x;
    s.y += a.y * a.y + b.y * b.y;
    s.z += a.z * a.z + b.z * b.z;
    s.w += a.w * a.w + b.w * b.w;
  }
  reinterpret_cast<float4*>(g_Spart + fc * (NB * NC * NFR) + bc * NFR)[q] = s;
}

// ---------------------------------------------------------------------------
// K2 (fused): reduce 8 partials -> g_S; block-reduce to s0; g_e/P_e scalars.
// grid 16 = one block per (b,c).
// ---------------------------------------------------------------------------
__global__ __launch_bounds__(256) void k_redgp() {
  int bc = blockIdx.x, tid = threadIdx.x;
  float4 s = make_float4(0.f, 0.f, 0.f, 0.f);
#pragma unroll
  for (int fc = 0; fc < 8; ++fc) {
    float4 a = reinterpret_cast<const float4*>(g_Spart + fc * (NB * NC * NFR) + bc * NFR)[tid];
    s.x += a.x; s.y += a.y; s.z += a.z; s.w += a.w;
  }
  reinterpret_cast<float4*>(g_S + bc * NFR)[tid] = s;
  float p = dpp_red_sum(s.x + s.y + s.z + s.w);
  __shared__ float r[4];
  if ((tid & 63) == 63) r[tid >> 6] = p;
  __syncthreads();
  if (tid == 0) {
    float s0 = (r[0] + r[1] + r[2] + r[3]) / (float)(NF * NFR);
    float P = 1.f;
#pragma unroll
    for (int e = 0; e < 3; ++e) {
      float g = fmaxf(s0 / P, 1e-5f);
      g_gP[e * 32 + bc] = g;
      g_gP[e * 32 + 16 + bc] = P;
      P *= g;
    }
  }
}

// Block-level reduction of 12 partials: DPP within wave, one barrier,
// b128 LDS round-trip, double-buffered by caller via `buf`.
__device__ __forceinline__ void block_reduce12(float* __restrict__ p,
                                               float (*red)[4][12], int buf,
                                               int lane, int wvid,
                                               float* __restrict__ s) {
#pragma unroll
  for (int k = 0; k < 12; ++k) p[k] = dpp_red_sum(p[k]);
  if (lane == 63) {
    float4* dst = reinterpret_cast<float4*>(&red[buf][wvid][0]);
    dst[0] = make_float4(p[0], p[1], p[2], p[3]);
    dst[1] = make_float4(p[4], p[5], p[6], p[7]);
    dst[2] = make_float4(p[8], p[9], p[10], p[11]);
  }
  __syncthreads();
  const float4* r = reinterpret_cast<const float4*>(&red[buf][0][0]);
#pragma unroll
  for (int k = 0; k < 3; ++k) {
    float4 a = r[0 + k], b = r[3 + k], c = r[6 + k], d = r[9 + k];
    s[4 * k + 0] = a.x + b.x + c.x + d.x;
    s[4 * k + 1] = a.y + b.y + c.y + d.y;
    s[4 * k + 2] = a.z + b.z + c.z + d.z;
    s[4 * k + 3] = a.w + b.w + c.w + d.w;
  }
}

// ---------------------------------------------------------------------------
// Main: one block per (b,f). Frames 4*tid..4*tid+3 per thread (float4 I/O).
// Xc in registers across all 36 ISS sweeps; DPP+LDS 12-float reduction with
// 1 barrier/sweep; W (4x4 cplx) in LDS; final solve + real(Xc*a) output.
// ---------------------------------------------------------------------------
__global__ __launch_bounds__(256) void k_main(const float* __restrict__ Xr,
                                              const float* __restrict__ Xi,
                                              float* __restrict__ out, int nout) {
  const int blk = blockIdx.x;
  const int b = blk / NF, f = blk % NF;
  const int tid = threadIdx.x;
  const int lane = tid & 63, wvid = tid >> 6;
  const float invN = 1.f / (float)NFR;

  __shared__ float red[2][4][12];
  __shared__ float Wre[NC][NC], Wim[NC][NC];
  __shared__ float abc[8];

  float xcr[NC][4], xci[NC][4];
  int rowbase[NC];
#pragma unroll
  for (int c = 0; c < NC; ++c) {
    rowbase[c] = ((b * NC + c) * NF + f) * NFR;
    float4 ar = reinterpret_cast<const float4*>(Xr + rowbase[c])[tid];
    float4 ai = reinterpret_cast<const float4*>(Xi + rowbase[c])[tid];
    xcr[c][0] = ar.x; xcr[c][1] = ar.y; xcr[c][2] = ar.z; xcr[c][3] = ar.w;
    xci[c][0] = ai.x; xci[c][1] = ai.y; xci[c][2] = ai.z; xci[c][3] = ai.w;
  }
  if (tid < 16) {
    Wre[tid >> 2][tid & 3] = ((tid >> 2) == (tid & 3)) ? 1.f : 0.f;
    Wim[tid >> 2][tid & 3] = 0.f;
  }
  // W-init visibility to thread 0: ordered by the first sweep's barrier.

  float w[NC][4];
  int buf = 0;

  for (int e = 0; e < 3; ++e) {
    // ---- per-epoch weights (closed form from S, g, P) ----
#pragma unroll
    for (int c = 0; c < NC; ++c) {
      float g = g_gP[e * 32 + b * NC + c];
      float P = g_gP[e * 32 + 16 + b * NC + c];
      float sc = 1.f / P;
      float4 Sv = reinterpret_cast<const float4*>(g_S + (b * NC + c) * NFR)[tid];
      w[c][0] = g / fmaxf(2.f * sqrtf(Sv.x * sc), EPS_MODEL);
      w[c][1] = g / fmaxf(2.f * sqrtf(Sv.y * sc), EPS_MODEL);
      w[c][2] = g / fmaxf(2.f * sqrtf(Sv.z * sc), EPS_MODEL);
      w[c][3] = g / fmaxf(2.f * sqrtf(Sv.w * sc), EPS_MODEL);
    }

    // ================= type-1 sweeps =================
    for (int src = 0; src < NC; ++src) {
      float p[12];
#pragma unroll
      for (int k = 0; k < 12; ++k) p[k] = 0.f;
#pragma unroll
      for (int j = 0; j < 4; ++j) {
        float xsr = xcr[src][j], xsi = xci[src][j];
        float msq = xsr * xsr + xsi * xsi;
#pragma unroll
        for (int c = 0; c < NC; ++c) {
          float wvv = w[c][j];
          p[c]     += wvv * (xcr[c][j] * xsr + xci[c][j] * xsi);
          p[4 + c] += wvv * (xci[c][j] * xsr - xcr[c][j] * xsi);
          p[8 + c] += wvv * msq;
        }
      }
      float s12[12];
      block_reduce12(p, red, buf, lane, wvid, s12);
      buf ^= 1;

      float vr[NC], vi[NC];
#pragma unroll
      for (int c = 0; c < NC; ++c) {
        float den = fmaxf(s12[8 + c] * invN, EPSV);
        if (c == src) {
          vr[c] = 1.f - 1.f / sqrtf(den);
          vi[c] = 0.f;
        } else {
          vr[c] = (s12[c] * invN) / den;
          vi[c] = (s12[4 + c] * invN) / den;
        }
      }
#pragma unroll
      for (int j = 0; j < 4; ++j) {
        float xsr = xcr[src][j], xsi = xci[src][j];
#pragma unroll
        for (int c = 0; c < NC; ++c) {
          xcr[c][j] -= vr[c] * xsr - vi[c] * xsi;
          xci[c][j] -= vr[c] * xsi + vi[c] * xsr;
        }
      }
      if (tid == 0) {
#pragma unroll
        for (int jj = 0; jj < NC; ++jj) {
          float wsr = Wre[src][jj], wsi = Wim[src][jj];
#pragma unroll
          for (int c = 0; c < NC; ++c) {
            Wre[c][jj] -= vr[c] * wsr - vi[c] * wsi;
            Wim[c][jj] -= vr[c] * wsi + vi[c] * wsr;
          }
        }
      }
    }

    // ================= type-2 sweeps =================
    for (int src = 0; src < NC; ++src) {
      const int sbase = ((b * NC + src) * NF + f) * NFR;
      // Shared 5-frame window [4t-3 .. 4t+1] of ORIGINAL X serves both taps.
      float wr[5], wi[5];
#pragma unroll
      for (int k = 0; k < 5; ++k) {
        int m = 4 * tid - 3 + k;
        bool ok = (m >= 0);
        wr[k] = ok ? Xr[sbase + m] : 0.f;
        wi[k] = ok ? Xi[sbase + m] : 0.f;
      }
      for (int tap = 0; tap < 2; ++tap) {
        float p[12];
#pragma unroll
        for (int k = 0; k < 12; ++k) p[k] = 0.f;
#pragma unroll
        for (int j = 0; j < 4; ++j) {
          float xsr = wr[j + tap], xsi = wi[j + tap];  // frame 4t+j-3+tap
          float msq = xsr * xsr + xsi * xsi;
#pragma unroll
          for (int c = 0; c < NC; ++c) {
            float wvv = w[c][j];
            p[c]     += wvv * (xcr[c][j] * xsr + xci[c][j] * xsi);
            p[4 + c] += wvv * (xci[c][j] * xsr - xcr[c][j] * xsi);
            p[8 + c] += wvv * msq;
          }
        }
        float s12[12];
        block_reduce12(p, red, buf, lane, wvid, s12);
        buf ^= 1;

        float vr[NC], vi[NC];
#pragma unroll
        for (int c = 0; c < NC; ++c) {
          float den = fmaxf(s12[8 + c], EPSV);  // SUM, not mean
          vr[c] = (s12[c] * invN) / den;
          vi[c] = (s12[4 + c] * invN) / den;
        }
#pragma unroll
        for (int j = 0; j < 4; ++j) {
          float xsr = wr[j + tap], xsi = wi[j + tap];
#pragma unroll
          for (int c = 0; c < NC; ++c) {
            xcr[c][j] -= vr[c] * xsr - vi[c] * xsi;
            xci[c][j] -= vr[c] * xsi + vi[c] * xsr;
          }
        }
      }
    }
  }  // epochs

  // ---- solve W^T a = e1 (4x4 complex, partial pivoting), A[i][j] = W[j][i] ----
  __syncthreads();
  if (tid == 0) {
    float Ar[4][4], Ai[4][4];
    float br[4] = {1.f, 0.f, 0.f, 0.f}, bi[4] = {0.f, 0.f, 0.f, 0.f};
#pragma unroll
    for (int i = 0; i < 4; ++i)
#pragma unroll
      for (int j = 0; j < 4; ++j) {
        Ar[i][j] = Wre[j][i];
        Ai[i][j] = Wim[j][i];
      }
    for (int k = 0; k < 4; ++k) {
      int piv = k;
      float best = Ar[k][k] * Ar[k][k] + Ai[k][k] * Ai[k][k];
      for (int i = k + 1; i < 4; ++i) {
        float m = Ar[i][k] * Ar[i][k] + Ai[i][k] * Ai[i][k];
        if (m > best) { best = m; piv = i; }
      }
      if (piv != k) {
        for (int j = 0; j < 4; ++j) {
          float t = Ar[k][j]; Ar[k][j] = Ar[piv][j]; Ar[piv][j] = t;
          t = Ai[k][j]; Ai[k][j] = Ai[piv][j]; Ai[piv][j] = t;
        }
        float t = br[k]; br[k] = br[piv]; br[piv] = t;
        t = bi[k]; bi[k] = bi[piv]; bi[piv] = t;
      }
      float dr = Ar[k][k], di = Ai[k][k];
      float inv = 1.f / (dr * dr + di * di);
      for (int i = k + 1; i < 4; ++i) {
        float fr = (Ar[i][k] * dr + Ai[i][k] * di) * inv;
        float fi = (Ai[i][k] * dr - Ar[i][k] * di) * inv;
        for (int j = k; j < 4; ++j) {
          Ar[i][j] -= fr * Ar[k][j] - fi * Ai[k][j];
          Ai[i][j] -= fr * Ai[k][j] + fi * Ar[k][j];
        }
        br[i] -= fr * br[k] - fi * bi[k];
        bi[i] -= fr * bi[k] + fi * br[k];
      }
    }
    float ar[4], ai[4];
    for (int k = 3; k >= 0; --k) {
      float sr = br[k], si = bi[k];
      for (int j = k + 1; j < 4; ++j) {
        sr -= Ar[k][j] * ar[j] - Ai[k][j] * ai[j];
        si -= Ar[k][j] * ai[j] + Ai[k][j] * ar[j];
      }
      float dr = Ar[k][k], di = Ai[k][k];
      float inv = 1.f / (dr * dr + di * di);
      ar[k] = (sr * dr + si * di) * inv;
      ai[k] = (si * dr - sr * di) * inv;
    }
#pragma unroll
    for (int c = 0; c < 4; ++c) { abc[c] = ar[c]; abc[4 + c] = ai[c]; }
  }
  __syncthreads();

  // ---- output: real(Xc * a), float4 per (c, thread), bounds-guarded ----
#pragma unroll
  for (int c = 0; c < NC; ++c) {
    float ar = abc[c], ai2 = abc[4 + c];
    if (rowbase[c] + 4 * tid + 3 < nout) {
      float4 o;
      o.x = xcr[c][0] * ar - xci[c][0] * ai2;
      o.y = xcr[c][1] * ar - xci[c][1] * ai2;
      o.z = xcr[c][2] * ar - xci[c][2] * ai2;
      o.w = xcr[c][3] * ar - xci[c][3] * ai2;
      reinterpret_cast<float4*>(out + rowbase[c])[tid] = o;
    }
  }
}

// ---------------------------------------------------------------------------
extern "C" void kernel_launch(void* const* d_in, const int* in_sizes, int n_in,
                              void* d_out, int out_size, void* d_ws, size_t ws_size,
                              hipStream_t stream) {
  const float* Xr = (const float*)d_in[0];
  const float* Xi = (const float*)d_in[1];
  float* out = (float*)d_out;

  dim3 g1(16, 8);
  k_colsum<<<g1, 256, 0, stream>>>(Xr, Xi);
  k_redgp<<<16, 256, 0, stream>>>();
  k_main<<<NB * NF, 256, 0, stream>>>(Xr, Xi, out, out_size);
}